// Round 22
// baseline (618.015 us; speedup 1.0000x reference)
//
#include <hip/hip_runtime.h>
#include <math.h>

// ---------------------------------------------------------------------------
// BMN forward on MI355X. B=2, T=100, DM=100, NS=32, NSPB=3, FEAT=400,
// H1=256, H2=128, H3=512.
// fmap: s-shift-invariant sample_mask => per-d entry table {ofs,w0,w1,cap},
// cell-merge (R6), o-pair float2 LDS (R9), clamp small-LDS (R11), wave-tile
// load balance (R18). qgemm n-split (R17). conv split-K (R14/R15/R19).
// float4 merges (R21).
// R22: conv3x3_sk3 + ISOLATED software prefetch (R12 bundled prefetch with
// 8-oc shrink and regressed; blamed the tile, prefetch-at-16oc untested.
// VGPR 16->28 is free at occ 53%; 144 fmacs hide the 9-load L2 chain).
// ---------------------------------------------------------------------------

#define PADW 154
#define PADL 52

// tab[d][96]: int4 {word_ofs, w0 bits, w1 bits, clamp_cap}; npd[d].
// ctab[d][64]: int2 {word_addr | starg<<16, w bits}; ncord[d].
__global__ void build_table_k(int4* __restrict__ tab, int* __restrict__ npd,
                              int2* __restrict__ ctab, int* __restrict__ ncord) {
  int d = threadIdx.x;
  if (d >= 100) return;
  double center = (double)d + 1.0;
  double step = (2.0 * d + 1.0) / 95.0;
  double xmin0 = -center * 0.5;
  int pp = 0, qq = 0;
  int lastfl = 1000, lastn = -1;
  for (int n = 0; n < 32; ++n) {
    double o[3];
    int f[3];
    double fr[3];
    for (int k = 0; k < 3; ++k) {
      o[k] = xmin0 + (double)(3 * n + k) * step;
      double fld = floor(o[k]);
      f[k] = (int)fld;
      fr[k] = o[k] - fld;  // [0,1)
    }
    // corrections (trunc-vs-floor: samp in (-1,0) -> net 1.0 at pos 0;
    // fast path gives fr/3 at cell 0 -> add (1-fr)/3 at lane s=-1-fl)
    for (int k = 0; k < 3; ++k) {
      if (f[k] < 0 && fr[k] > 0.0) {
        float cw = (float)((1.0 - fr[k]) / 3.0);
        int st = -1 - f[k];  // in [0,50]
        if (qq > 0 && f[k] == lastfl && n == lastn) {
          int2 pe = ctab[d * 64 + qq - 1];
          pe.y = __float_as_int(__int_as_float(pe.y) + cw);
          ctab[d * 64 + qq - 1] = pe;
        } else if (qq < 64) {
          int2 e;
          e.x = (n * PADW + PADL) | (st << 16);
          e.y = __float_as_int(cw);
          ctab[d * 64 + qq] = e;
          ++qq;
          lastfl = f[k];
          lastn = n;
        }
      }
    }
    // entries: choose cheaper of tap-list vs cell-merged run
    int lo = f[0];
    int hi = f[2] + 1;
    if (hi > 99) hi = 99;      // cells >99 are zero-data
    if (lo > 99) continue;     // whole bin dead for all s
    int cap = n * PADW + PADL + 100;  // qsp[cap]=qsp[cap+1]=0
    int L = hi - lo + 1;
    int ec = (L + 1) >> 1;
    if (ec < 3) {
      // cell-merge: L <= 4
      double cw[6] = {0, 0, 0, 0, 0, 0};
      for (int k = 0; k < 3; ++k) {
        int c0 = f[k] - lo;
        if (c0 >= 0 && c0 <= hi - lo) cw[c0] += 1.0 - fr[k];
        int c1 = f[k] + 1 - lo;
        if (c1 >= 0 && c1 <= hi - lo) cw[c1] += fr[k];
      }
      for (int c = 0; c <= hi - lo; c += 2) {
        int4 e;
        e.x = n * PADW + PADL + lo + c;
        e.y = __float_as_int((float)(cw[c] / 3.0));
        e.z = __float_as_int((c + 1 <= hi - lo) ? (float)(cw[c + 1] / 3.0) : 0.f);
        e.w = cap;
        tab[d * 96 + pp] = e;
        ++pp;
      }
    } else {
      for (int k = 0; k < 3; ++k) {
        if (f[k] > 99) continue;
        int4 e;
        e.x = n * PADW + PADL + f[k];
        e.y = __float_as_int((float)((1.0 - fr[k]) / 3.0));
        e.z = __float_as_int((float)(fr[k] / 3.0));
        e.w = cap;
        tab[d * 96 + pp] = e;
        ++pp;
      }
    }
  }
  npd[d] = pp;
  while (qq & 3) {  // pad corrections (st=127 never matches)
    int2 z;
    z.x = 127 << 16; z.y = 0;
    ctab[d * 64 + qq] = z;
    ++qq;
  }
  ncord[d] = qq;
}

// transpose conv2d weights for uniform (scalar) access
__global__ void prep_w_k(const float* __restrict__ w_c1, const float* __restrict__ w_c2,
                         const float* __restrict__ w_c3, float* __restrict__ wT1,
                         float* __restrict__ wT2, float* __restrict__ wT3) {
  int idx = blockIdx.x * 256 + threadIdx.x;
  if (idx < 512 * 128) {
    int c = idx >> 7, oc = idx & 127;
    wT1[idx] = w_c1[oc * 512 + c];
  }
  if (idx < 128 * 9 * 128) {
    int oc = idx & 127;
    int r = idx >> 7;
    int c = r / 9, tap = r % 9;
    wT2[idx] = w_c2[(oc * 128 + c) * 9 + tap];
    wT3[idx] = w_c3[(oc * 128 + c) * 9 + tap];
  }
}

// k=3 pad=1 grouped conv1d + relu, 4-way channel split.
// grid.x = B*Cout, block = 512 (4 cg x 128 t)
__global__ __launch_bounds__(512) void conv1d_k3s(
    const float* __restrict__ in, const float* __restrict__ wt,
    const float* __restrict__ bias, float* __restrict__ out,
    int Cin_total, int Cin_g, int Cout, int ocpg) {
  __shared__ float part[512];
  int bo = blockIdx.x;
  int o = bo % Cout, b = bo / Cout, g = o / ocpg;
  int tid = threadIdx.x;
  int cg = __builtin_amdgcn_readfirstlane(tid >> 7);  // wave-uniform
  int t = tid & 127;
  int tc = t < 100 ? t : 99;
  int cpc = Cin_g >> 2;
  const float* ib = in + ((size_t)b * Cin_total + (size_t)g * Cin_g + (size_t)cg * cpc) * 100;
  const float* wr = wt + ((size_t)o * Cin_g + (size_t)cg * cpc) * 3;
  float acc = 0.f;
#pragma unroll 4
  for (int c = 0; c < cpc; ++c) {
    const float* row = ib + c * 100;
    float w0 = wr[c * 3 + 0], w1 = wr[c * 3 + 1], w2 = wr[c * 3 + 2];
    float a = (tc > 0) ? row[tc - 1] : 0.f;
    float m = row[tc];
    float z = (tc < 99) ? row[tc + 1] : 0.f;
    acc += w0 * a + w1 * m + w2 * z;
  }
  part[tid] = acc;
  __syncthreads();
  if (cg == 0 && t < 100) {
    float a = part[t] + part[128 + t] + part[256 + t] + part[384 + t] + bias[o];
    out[(size_t)bo * 100 + t] = fmaxf(a, 0.f);
  }
}

// dual-branch version: blocks [0,512) -> A (s-branch), [512,1024) -> B (e-branch)
__global__ __launch_bounds__(512) void conv1d_k3s_dual(
    const float* __restrict__ in,
    const float* __restrict__ wA, const float* __restrict__ bA, float* __restrict__ outA,
    const float* __restrict__ wB, const float* __restrict__ bB, float* __restrict__ outB,
    int Cin_total, int Cin_g, int Cout, int ocpg) {
  __shared__ float part[512];
  int bx = blockIdx.x;
  bool second = bx >= 512;
  int bo = second ? bx - 512 : bx;
  const float* wt = second ? wB : wA;
  const float* bias = second ? bB : bA;
  float* out = second ? outB : outA;
  int o = bo % Cout, b = bo / Cout, g = o / ocpg;
  int tid = threadIdx.x;
  int cg = __builtin_amdgcn_readfirstlane(tid >> 7);
  int t = tid & 127;
  int tc = t < 100 ? t : 99;
  int cpc = Cin_g >> 2;
  const float* ib = in + ((size_t)b * Cin_total + (size_t)g * Cin_g + (size_t)cg * cpc) * 100;
  const float* wr = wt + ((size_t)o * Cin_g + (size_t)cg * cpc) * 3;
  float acc = 0.f;
#pragma unroll 4
  for (int c = 0; c < cpc; ++c) {
    const float* row = ib + c * 100;
    float w0 = wr[c * 3 + 0], w1 = wr[c * 3 + 1], w2 = wr[c * 3 + 2];
    float a = (tc > 0) ? row[tc - 1] : 0.f;
    float m = row[tc];
    float z = (tc < 99) ? row[tc + 1] : 0.f;
    acc += w0 * a + w1 * m + w2 * z;
  }
  part[tid] = acc;
  __syncthreads();
  if (cg == 0 && t < 100) {
    float a = part[t] + part[128 + t] + part[256 + t] + part[384 + t] + bias[o];
    out[(size_t)bo * 100 + t] = fmaxf(a, 0.f);
  }
}

// dense p-conv1d, SPLIT-K raw partials. grid=(512,2), block=512 (4cg x 128t);
// kz selects channels [kz*128, kz*128+128), cg covers 32 within that.
__global__ __launch_bounds__(512) void conv1d_p_sk(
    const float* __restrict__ in, const float* __restrict__ wt,
    float* __restrict__ dst0, float* __restrict__ dst1) {
  __shared__ float part[512];
  int bo = blockIdx.x;              // b*256+o
  int kz = blockIdx.y;
  float* dst = kz ? dst1 : dst0;
  int o = bo & 255, b = bo >> 8;
  int tid = threadIdx.x;
  int cg = __builtin_amdgcn_readfirstlane(tid >> 7);
  int t = tid & 127;
  int tc = t < 100 ? t : 99;
  int cbase = kz * 128 + cg * 32;
  const float* ib = in + ((size_t)b * 256 + cbase) * 100;
  const float* wr = wt + ((size_t)o * 256 + cbase) * 3;
  float acc = 0.f;
#pragma unroll 4
  for (int c = 0; c < 32; ++c) {
    const float* row = ib + c * 100;
    float w0 = wr[c * 3 + 0], w1 = wr[c * 3 + 1], w2 = wr[c * 3 + 2];
    float a = (tc > 0) ? row[tc - 1] : 0.f;
    float m = row[tc];
    float z = (tc < 99) ? row[tc + 1] : 0.f;
    acc += w0 * a + w1 * m + w2 * z;
  }
  part[tid] = acc;
  __syncthreads();
  if (cg == 0 && t < 100) {
    float a = part[t] + part[128 + t] + part[256 + t] + part[384 + t];
    dst[(size_t)bo * 100 + t] = a;  // raw partial
  }
}

// merge p partials (float4): p = relu(p0 + p1 + bias[o]). 12800 vec4, grid=50
__global__ void merge_p_k(const float4* __restrict__ p0, const float4* __restrict__ p1,
                          const float* __restrict__ bias, float4* __restrict__ p) {
  int i = blockIdx.x * 256 + threadIdx.x;
  if (i >= 12800) return;
  int o = ((i * 4) / 100) & 255;   // 100 % 4 == 0: all 4 share o
  float bo = bias[o];
  float4 a = p0[i], b = p1[i], r;
  r.x = fmaxf(a.x + b.x + bo, 0.f);
  r.y = fmaxf(a.y + b.y + bo, 0.f);
  r.z = fmaxf(a.z + b.z + bo, 0.f);
  r.w = fmaxf(a.w + b.w + bo, 0.f);
  p[i] = r;
}

// dual 1x1->1 heads + sigmoid. grid=400: [0,200) start, [200,400) end. block=64
__global__ void head_sig_dual(const float* __restrict__ midA, const float* __restrict__ wA,
                              const float* __restrict__ bA, float* __restrict__ outA,
                              const float* __restrict__ midB, const float* __restrict__ wB,
                              const float* __restrict__ bB, float* __restrict__ outB) {
  int bx = blockIdx.x;
  bool second = bx >= 200;
  int idx = second ? bx - 200 : bx;
  const float* mid = second ? midB : midA;
  const float* w = second ? wB : wA;
  const float* bias = second ? bB : bA;
  float* out = second ? outB : outA;
  int b = idx / 100, t = idx % 100;
  int l = threadIdx.x;
  float acc = 0.f;
#pragma unroll
  for (int c0 = 0; c0 < 256; c0 += 64)
    acc += mid[((size_t)b * 256 + c0 + l) * 100 + t] * w[c0 + l];
#pragma unroll
  for (int off = 32; off; off >>= 1) acc += __shfl_down(acc, off);
  if (l == 0) out[idx] = 1.f / (1.f + expf(-(acc + bias[0])));
}

// q[b,o,n,pos] = sum_c w3d[o,c,n] p[b,c,pos]. grid = 1024 (b*512+o),
// block 512 = 4 n-groups x 128 lanes(pos); group ng owns n in [8ng, 8ng+8).
__global__ __launch_bounds__(512) void qgemm_k(
    const float* __restrict__ p, const float* __restrict__ w3d,
    float* __restrict__ q) {
  int bb = blockIdx.x;
  int b = bb >> 9, o = bb & 511;
  int tid = threadIdx.x;
  int ng = __builtin_amdgcn_readfirstlane(tid >> 7);  // wave-uniform n group
  int pos = tid & 127;
  int pc = pos < 100 ? pos : 99;
  const float* pb = p + (size_t)b * 25600;
  const float* wr = w3d + (size_t)o * 8192 + ng * 8;
  float acc[8];
#pragma unroll
  for (int j = 0; j < 8; ++j) acc[j] = 0.f;
#pragma unroll 2
  for (int c = 0; c < 256; ++c) {
    float v = pb[c * 100 + pc];
    const float* w = wr + c * 32;
#pragma unroll
    for (int j = 0; j < 8; ++j) acc[j] += v * w[j];
  }
  if (pos < 100) {
#pragma unroll
    for (int j = 0; j < 8; ++j)
      q[((size_t)(bb * 32 + ng * 8 + j)) * 100 + pos] = acc[j];
  }
}

// fmap for an o-PAIR. grid=(512,5), block 512 = 8 waves (R18 wave-tiling).
__global__ __launch_bounds__(512) void fmap_k2(
    const float* __restrict__ q, const int4* __restrict__ tab,
    const int* __restrict__ npd, const int2* __restrict__ ctab,
    const int* __restrict__ ncord, const float* __restrict__ b3d,
    float* __restrict__ out) {
  __shared__ float2 qsp[32 * PADW];  // 39424 B -> 4 blocks/CU
  int bo0 = blockIdx.x * 2;
  int bo1 = bo0 + 1;
  const float* qa = q + (size_t)bo0 * 3200;
  const float* qb = q + (size_t)bo1 * 3200;
  for (int i = threadIdx.x; i < 32 * PADW; i += 512) qsp[i] = make_float2(0.f, 0.f);
  __syncthreads();
  for (int i = threadIdx.x; i < 3200; i += 512) {
    int n = i / 100;
    qsp[n * PADW + PADL + (i - n * 100)] = make_float2(qa[i], qb[i]);
  }
  __syncthreads();
  int w = __builtin_amdgcn_readfirstlane(threadIdx.x >> 6);  // wave id 0..7
  int lane = threadIdx.x & 63;
  int dbase = __builtin_amdgcn_readfirstlane(blockIdx.y * 20);
  int v1 = 36 - dbase;
  v1 = v1 < 0 ? 0 : (v1 > 20 ? 20 : v1);   // half-1 tiles with any valid lane
  int ntiles = 20 + v1;
  float biasA = b3d[bo0 & 511];
  float biasB = b3d[bo1 & 511];
  for (int tt = w; tt < ntiles; tt += 8) {   // wave-uniform loop
    int half = tt >= 20;
    int d = __builtin_amdgcn_readfirstlane(dbase + (half ? tt - 20 : tt));
    int s = (half << 6) + lane;
    int sc = s < 100 ? s : 99;
    const int4* td = tab + d * 96;
    int np = npd[d];
    float a0 = 0.f, a1 = 0.f, b0 = 0.f, b1 = 0.f;
    for (int j = 0; j < np; ++j) {
      int4 e = td[j];     // s_load (uniform): ofs+weights+cap in SGPRs
      int i0 = min(e.x + sc, e.w);   // clamp into per-row zero cells
      float2 v0 = qsp[i0];
      float2 v1f = qsp[i0 + 1];
      float w0 = __int_as_float(e.y);
      float w1 = __int_as_float(e.z);
      a0 += w0 * v0.x;
      b0 += w0 * v0.y;
      a1 += w1 * v1f.x;
      b1 += w1 * v1f.y;
    }
    if (!half) {  // corrections only target lanes s <= 50
      const int2* cd = ctab + d * 64;
      int nc = ncord[d];
      for (int j = 0; j < nc; ++j) {
        int2 c = cd[j];   // s_load
        int addr = c.x & 0xFFFF;
        int st = c.x >> 16;
        float wgt = (s == st) ? __int_as_float(c.y) : 0.f;
        float2 v = qsp[addr];
        a0 += wgt * v.x;
        b0 += wgt * v.y;
      }
    }
    if (s < 100) {
      bool valid = (s + d < 100);
      float preA = biasA + (valid ? (a0 + a1) : 0.f);
      float preB = biasB + (valid ? (b0 + b1) : 0.f);
      out[((size_t)bo0 * 100 + d) * 100 + s] = fmaxf(preA, 0.f);
      out[((size_t)bo1 * 100 + d) * 100 + s] = fmaxf(preB, 0.f);
    }
  }
  // dead region: half-1 tiles for d in [dbase+v1, dbase+20), s in [64,100)
  int ndead = (20 - v1) * 36;
  float cA = fmaxf(biasA, 0.f);
  float cB = fmaxf(biasB, 0.f);
  for (int idx = threadIdx.x; idx < ndead; idx += 512) {
    int dd = idx / 36;
    int ss = 64 + idx - dd * 36;
    int d = dbase + v1 + dd;
    out[((size_t)bo0 * 100 + d) * 100 + ss] = cA;
    out[((size_t)bo1 * 100 + d) * 100 + ss] = cB;
  }
}

// 1x1 conv 512->128, SPLIT-K raw partials. grid=(200,8,2), block=128, 16 oc;
// kz selects c-range [kz*256,(kz+1)*256); dst0 for kz=0, dst1 for kz=1.
__global__ void conv1x1_sk(const float* __restrict__ in, const float* __restrict__ wT,
                           float* __restrict__ dst0, float* __restrict__ dst1) {
  int bd = blockIdx.x;
  int y = bd % 100;
  int b = bd / 100;
  int oc0 = blockIdx.y * 16;
  int kz = blockIdx.z;
  float* dst = kz ? dst1 : dst0;
  int t = threadIdx.x;
  int tc = t < 100 ? t : 99;
  float acc[16];
#pragma unroll
  for (int j = 0; j < 16; ++j) acc[j] = 0.f;
  const float* inb = in + (size_t)b * 5120000 + (size_t)(kz * 256) * 10000 +
                     (size_t)y * 100 + tc;
  const float* wb = wT + (size_t)(kz * 256) * 128;
  for (int c = 0; c < 256; ++c) {
    float v = inb[(size_t)c * 10000];
    const float* w = wb + c * 128 + oc0;
#pragma unroll
    for (int j = 0; j < 16; ++j) acc[j] += v * w[j];
  }
  if (t < 100) {
#pragma unroll
    for (int j = 0; j < 16; ++j)
      dst[((size_t)(b * 128 + oc0 + j) * 100 + y) * 100 + t] = acc[j];
  }
}

// 3x3 conv 128->128 pad 1, SPLIT-K(3) raw partials + software prefetch.
// grid=(200,8,3), block=128, 16 oc; kz c-ranges {0..42, 43..85, 86..127}.
__global__ void conv3x3_sk3(const float* __restrict__ in, const float* __restrict__ wT,
                            float* __restrict__ dst0, float* __restrict__ dst1,
                            float* __restrict__ dst2) {
  int bd = blockIdx.x;
  int y = bd % 100;
  int b = bd / 100;
  int oc0 = blockIdx.y * 16;
  int kz = blockIdx.z;
  int c0 = kz * 43;
  int cend = (kz == 2) ? 128 : c0 + 43;
  float* dst = (kz == 0) ? dst0 : ((kz == 1) ? dst1 : dst2);
  int t = threadIdx.x;
  int tc = t < 100 ? t : 99;
  bool okm = tc > 0, okp = tc < 99;
  bool oky0 = y > 0, oky2 = y < 99;
  const float* ib0 = in + (size_t)(b * 128) * 10000 + (size_t)y * 100 + tc;
  float acc[16];
#pragma unroll
  for (int j = 0; j < 16; ++j) acc[j] = 0.f;
  float vm[3], v0[3], vp[3];
  {  // preload first channel
    const float* pc = ib0 + (size_t)c0 * 10000;
#pragma unroll
    for (int ky = 0; ky < 3; ++ky) {
      bool oky = (ky == 0) ? oky0 : ((ky == 2) ? oky2 : true);
      const float* row = pc + (ky - 1) * 100;
      vm[ky] = (oky && okm) ? row[-1] : 0.f;
      v0[ky] = oky ? row[0] : 0.f;
      vp[ky] = (oky && okp) ? row[1] : 0.f;
    }
  }
  for (int c = c0; c < cend; ++c) {
    float nm[3], n0[3], np[3];
    if (c + 1 < cend) {  // prefetch next channel's 9 taps during fmacs
      const float* pn = ib0 + (size_t)(c + 1) * 10000;
#pragma unroll
      for (int ky = 0; ky < 3; ++ky) {
        bool oky = (ky == 0) ? oky0 : ((ky == 2) ? oky2 : true);
        const float* row = pn + (ky - 1) * 100;
        nm[ky] = (oky && okm) ? row[-1] : 0.f;
        n0[ky] = oky ? row[0] : 0.f;
        np[ky] = (oky && okp) ? row[1] : 0.f;
      }
    }
    const float* wc = wT + ((size_t)c * 9) * 128 + oc0;
#pragma unroll
    for (int ky = 0; ky < 3; ++ky) {
      const float* wk = wc + (size_t)(ky * 3) * 128;
#pragma unroll
      for (int j = 0; j < 16; ++j)
        acc[j] += vm[ky] * wk[j] + v0[ky] * wk[128 + j] + vp[ky] * wk[256 + j];
    }
#pragma unroll
    for (int ky = 0; ky < 3; ++ky) {
      vm[ky] = nm[ky];
      v0[ky] = n0[ky];
      vp[ky] = np[ky];
    }
  }
  if (t < 100) {
#pragma unroll
    for (int j = 0; j < 16; ++j)
      dst[((size_t)(b * 128 + oc0 + j) * 100 + y) * 100 + t] = acc[j];
  }
}

// merge 2 split-K partials (float4): io = relu(io + pA + bias[oc]).
// 640000 vec4, grid=2500. 10000 % 4 == 0 -> all 4 elems share oc.
__global__ void merge_relu_k(const float4* __restrict__ pA, float4* __restrict__ io,
                             const float* __restrict__ bias) {
  int i = blockIdx.x * 256 + threadIdx.x;
  if (i >= 640000) return;
  int oc = ((i * 4) / 10000) & 127;
  float bo = bias[oc];
  float4 a = pA[i], b = io[i], r;
  r.x = fmaxf(a.x + b.x + bo, 0.f);
  r.y = fmaxf(a.y + b.y + bo, 0.f);
  r.z = fmaxf(a.z + b.z + bo, 0.f);
  r.w = fmaxf(a.w + b.w + bo, 0.f);
  io[i] = r;
}

// merge 3 split-K partials (float4): io = relu(io + pA + pB + bias[oc]).
__global__ void merge_relu3_k(const float4* __restrict__ pA, const float4* __restrict__ pB,
                              float4* __restrict__ io, const float* __restrict__ bias) {
  int i = blockIdx.x * 256 + threadIdx.x;
  if (i >= 640000) return;
  int oc = ((i * 4) / 10000) & 127;
  float bo = bias[oc];
  float4 a = pA[i], b = pB[i], c = io[i], r;
  r.x = fmaxf(a.x + b.x + c.x + bo, 0.f);
  r.y = fmaxf(a.y + b.y + c.y + bo, 0.f);
  r.z = fmaxf(a.z + b.z + c.z + bo, 0.f);
  r.w = fmaxf(a.w + b.w + c.w + bo, 0.f);
  io[i] = r;
}

// final 1x1 conv 128->2 + sigmoid. grid=625, block=256 (64 sp x 4 c-groups)
__global__ void conv1x1_final(const float* __restrict__ in, const float* __restrict__ w,
                              const float* __restrict__ bias, float* __restrict__ out) {
  __shared__ float part[256];
  int tid = threadIdx.x;
  int spl = tid & 63, cg = tid >> 6;
  int idx = blockIdx.x * 64 + spl;
  bool ok = idx < 40000;
  int ic = ok ? idx : 0;
  int sp = ic % 10000;
  int i = (ic / 10000) & 1;
  int b = ic / 20000;
  const float* ib = in + (size_t)b * 1280000 + (size_t)cg * 320000 + sp;
  const float* wp = w + i * 128 + cg * 32;
  float acc = 0.f;
#pragma unroll 8
  for (int c = 0; c < 32; ++c)
    acc += ib[(size_t)c * 10000] * wp[c];
  part[tid] = acc;
  __syncthreads();
  if (cg == 0 && ok) {
    float a = part[spl] + part[64 + spl] + part[128 + spl] + part[192 + spl] + bias[i];
    out[idx] = 1.f / (1.f + expf(-a));
  }
}

extern "C" void kernel_launch(void* const* d_in, const int* in_sizes, int n_in,
                              void* d_out, int out_size, void* d_ws, size_t ws_size,
                              hipStream_t stream) {
  const float* x    = (const float*)d_in[0];
  const float* w_b1 = (const float*)d_in[1];
  const float* b_b1 = (const float*)d_in[2];
  const float* w_b2 = (const float*)d_in[3];
  const float* b_b2 = (const float*)d_in[4];
  const float* w_s1 = (const float*)d_in[5];
  const float* b_s1 = (const float*)d_in[6];
  const float* w_s2 = (const float*)d_in[7];
  const float* b_s2 = (const float*)d_in[8];
  const float* w_e1 = (const float*)d_in[9];
  const float* b_e1 = (const float*)d_in[10];
  const float* w_e2 = (const float*)d_in[11];
  const float* b_e2 = (const float*)d_in[12];
  const float* w_p  = (const float*)d_in[13];
  const float* b_p  = (const float*)d_in[14];
  const float* w_3d = (const float*)d_in[15];
  const float* b_3d = (const float*)d_in[16];
  const float* w_c1 = (const float*)d_in[17];
  const float* b_c1 = (const float*)d_in[18];
  const float* w_c2 = (const float*)d_in[19];
  const float* b_c2 = (const float*)d_in[20];
  const float* w_c3 = (const float*)d_in[21];
  const float* b_c3 = (const float*)d_in[22];
  const float* w_c4 = (const float*)d_in[23];
  const float* b_c4 = (const float*)d_in[24];
  // d_in[25] = sample_mask (unused: replaced by analytic table)

  float* out = (float*)d_out;
  float* ws  = (float*)d_ws;

  // workspace layout (float offsets); peak 10,959,104 floats = 43.8 MB
  float* h1  = ws;                        // 51200
  float* h2  = ws + 51200;                // 51200
  float* mid = ws + 102400;               // 51200 (s-branch)
  float* p   = ws + 153600;               // 51200
  int4*  tab   = (int4*)(ws + 204800);    // 9600 int4 = 38400
  int*   npd   = (int*)(ws + 243200);     // 128
  int2*  ctab  = (int2*)(ws + 243328);    // 6400 int2 = 12800
  int*   ncord = (int*)(ws + 256128);     // 128
  float* wT1 = ws + 256256;               // 65536
  float* wT2 = ws + 321792;               // 147456
  float* wT3 = ws + 469248;               // 147456
  float* q   = ws + 616704;               // 3,276,800 (dead after fmap_k2)
  float* c1b = ws + 616704;               // 2,560,000 (reuses q)
  float* c2b = ws + 3176704;              // 2,560,000
  float* mid_e = ws + 3176704;            // 51200 (dead before c2b written)
  float* pA  = ws + 5736704;              // 2,560,000 (split-K partial)
  float* pP0 = ws + 8296704;              // 51200 (p-conv partial kz=0)
  float* pP1 = ws + 8347904;              // 51200 (p-conv partial kz=1)
  float* pB  = ws + 8399104;              // 2,560,000 (split-K partial #2)

  float* out_conf  = out;                 // 40,000
  float* out_start = out + 40000;         // 200
  float* out_end   = out + 40200;         // 200
  float* out_fmap  = out + 40400;         // 10,240,000

  hipLaunchKernelGGL(build_table_k, dim3(1), dim3(128), 0, stream,
                     tab, npd, ctab, ncord);
  hipLaunchKernelGGL(prep_w_k, dim3(576), dim3(256), 0, stream,
                     w_c1, w_c2, w_c3, wT1, wT2, wT3);

  hipLaunchKernelGGL(conv1d_k3s, dim3(512), dim3(512), 0, stream,
                     x, w_b1, b_b1, h1, 400, 100, 256, 64);
  hipLaunchKernelGGL(conv1d_k3s, dim3(512), dim3(512), 0, stream,
                     h1, w_b2, b_b2, h2, 256, 64, 256, 64);

  hipLaunchKernelGGL(conv1d_k3s_dual, dim3(1024), dim3(512), 0, stream,
                     h2, w_s1, b_s1, mid, w_e1, b_e1, mid_e, 256, 64, 256, 64);
  hipLaunchKernelGGL(head_sig_dual, dim3(400), dim3(64), 0, stream,
                     mid, w_s2, b_s2, out_start, mid_e, w_e2, b_e2, out_end);

  // dense p-conv: split-K partials + merge
  hipLaunchKernelGGL(conv1d_p_sk, dim3(512, 2), dim3(512), 0, stream,
                     h2, w_p, pP0, pP1);
  hipLaunchKernelGGL(merge_p_k, dim3(50), dim3(256), 0, stream,
                     (const float4*)pP0, (const float4*)pP1, b_p, (float4*)p);

  hipLaunchKernelGGL(qgemm_k, dim3(1024), dim3(512), 0, stream, p, w_3d, q);

  hipLaunchKernelGGL(fmap_k2, dim3(512, 5), dim3(512), 0, stream,
                     q, tab, npd, ctab, ncord, b_3d, out_fmap);

  // conv1x1: split-K partials (kz=0 -> pA, kz=1 -> c1b), merge into c1b
  hipLaunchKernelGGL(conv1x1_sk, dim3(200, 8, 2), dim3(128), 0, stream,
                     out_fmap, wT1, pA, c1b);
  hipLaunchKernelGGL(merge_relu_k, dim3(2500), dim3(256), 0, stream,
                     (const float4*)pA, (float4*)c1b, b_c1);

  // conv3x3 layer 1: kz=3 partials (pA, pB, c2b), 3-way merge into c2b
  hipLaunchKernelGGL(conv3x3_sk3, dim3(200, 8, 3), dim3(128), 0, stream,
                     c1b, wT2, pA, pB, c2b);
  hipLaunchKernelGGL(merge_relu3_k, dim3(2500), dim3(256), 0, stream,
                     (const float4*)pA, (const float4*)pB, (float4*)c2b, b_c2);

  // conv3x3 layer 2: input c2b; kz=3 partials (pA, pB, c1b), merge c1b
  hipLaunchKernelGGL(conv3x3_sk3, dim3(200, 8, 3), dim3(128), 0, stream,
                     c2b, wT3, pA, pB, c1b);
  hipLaunchKernelGGL(merge_relu3_k, dim3(2500), dim3(256), 0, stream,
                     (const float4*)pA, (const float4*)pB, (float4*)c1b, b_c3);

  hipLaunchKernelGGL(conv1x1_final, dim3(625), dim3(256), 0, stream,
                     c1b, w_c4, b_c4, out_conf);
}

// Round 23
// 515.120 us; speedup vs baseline: 1.1997x; 1.1997x over previous
//
#include <hip/hip_runtime.h>
#include <math.h>

// ---------------------------------------------------------------------------
// BMN forward on MI355X. B=2, T=100, DM=100, NS=32, NSPB=3, FEAT=400,
// H1=256, H2=128, H3=512.
// FINAL (R21 config, best: 515.9us from 2118us baseline):
// fmap: s-shift-invariant sample_mask => per-d entry table {ofs,w0,w1,cap},
// cell-merge (R6), o-pair float2 LDS (R9), clamp small-LDS (R11), wave-tile
// load balance (R18). qgemm n-split (R17). conv split-K (R14/R15/R19).
// float4 merges (R21). Prefetch refuted twice (R12, R22: VGPR 16->48,
// 114->167us); split-K TLP is the only working latency lever, saturated.
// ---------------------------------------------------------------------------

#define PADW 154
#define PADL 52

// tab[d][96]: int4 {word_ofs, w0 bits, w1 bits, clamp_cap}; npd[d].
// ctab[d][64]: int2 {word_addr | starg<<16, w bits}; ncord[d].
__global__ void build_table_k(int4* __restrict__ tab, int* __restrict__ npd,
                              int2* __restrict__ ctab, int* __restrict__ ncord) {
  int d = threadIdx.x;
  if (d >= 100) return;
  double center = (double)d + 1.0;
  double step = (2.0 * d + 1.0) / 95.0;
  double xmin0 = -center * 0.5;
  int pp = 0, qq = 0;
  int lastfl = 1000, lastn = -1;
  for (int n = 0; n < 32; ++n) {
    double o[3];
    int f[3];
    double fr[3];
    for (int k = 0; k < 3; ++k) {
      o[k] = xmin0 + (double)(3 * n + k) * step;
      double fld = floor(o[k]);
      f[k] = (int)fld;
      fr[k] = o[k] - fld;  // [0,1)
    }
    // corrections (trunc-vs-floor: samp in (-1,0) -> net 1.0 at pos 0;
    // fast path gives fr/3 at cell 0 -> add (1-fr)/3 at lane s=-1-fl)
    for (int k = 0; k < 3; ++k) {
      if (f[k] < 0 && fr[k] > 0.0) {
        float cw = (float)((1.0 - fr[k]) / 3.0);
        int st = -1 - f[k];  // in [0,50]
        if (qq > 0 && f[k] == lastfl && n == lastn) {
          int2 pe = ctab[d * 64 + qq - 1];
          pe.y = __float_as_int(__int_as_float(pe.y) + cw);
          ctab[d * 64 + qq - 1] = pe;
        } else if (qq < 64) {
          int2 e;
          e.x = (n * PADW + PADL) | (st << 16);
          e.y = __float_as_int(cw);
          ctab[d * 64 + qq] = e;
          ++qq;
          lastfl = f[k];
          lastn = n;
        }
      }
    }
    // entries: choose cheaper of tap-list vs cell-merged run
    int lo = f[0];
    int hi = f[2] + 1;
    if (hi > 99) hi = 99;      // cells >99 are zero-data
    if (lo > 99) continue;     // whole bin dead for all s
    int cap = n * PADW + PADL + 100;  // qsp[cap]=qsp[cap+1]=0
    int L = hi - lo + 1;
    int ec = (L + 1) >> 1;
    if (ec < 3) {
      // cell-merge: L <= 4
      double cw[6] = {0, 0, 0, 0, 0, 0};
      for (int k = 0; k < 3; ++k) {
        int c0 = f[k] - lo;
        if (c0 >= 0 && c0 <= hi - lo) cw[c0] += 1.0 - fr[k];
        int c1 = f[k] + 1 - lo;
        if (c1 >= 0 && c1 <= hi - lo) cw[c1] += fr[k];
      }
      for (int c = 0; c <= hi - lo; c += 2) {
        int4 e;
        e.x = n * PADW + PADL + lo + c;
        e.y = __float_as_int((float)(cw[c] / 3.0));
        e.z = __float_as_int((c + 1 <= hi - lo) ? (float)(cw[c + 1] / 3.0) : 0.f);
        e.w = cap;
        tab[d * 96 + pp] = e;
        ++pp;
      }
    } else {
      for (int k = 0; k < 3; ++k) {
        if (f[k] > 99) continue;
        int4 e;
        e.x = n * PADW + PADL + f[k];
        e.y = __float_as_int((float)((1.0 - fr[k]) / 3.0));
        e.z = __float_as_int((float)(fr[k] / 3.0));
        e.w = cap;
        tab[d * 96 + pp] = e;
        ++pp;
      }
    }
  }
  npd[d] = pp;
  while (qq & 3) {  // pad corrections (st=127 never matches)
    int2 z;
    z.x = 127 << 16; z.y = 0;
    ctab[d * 64 + qq] = z;
    ++qq;
  }
  ncord[d] = qq;
}

// transpose conv2d weights for uniform (scalar) access
__global__ void prep_w_k(const float* __restrict__ w_c1, const float* __restrict__ w_c2,
                         const float* __restrict__ w_c3, float* __restrict__ wT1,
                         float* __restrict__ wT2, float* __restrict__ wT3) {
  int idx = blockIdx.x * 256 + threadIdx.x;
  if (idx < 512 * 128) {
    int c = idx >> 7, oc = idx & 127;
    wT1[idx] = w_c1[oc * 512 + c];
  }
  if (idx < 128 * 9 * 128) {
    int oc = idx & 127;
    int r = idx >> 7;
    int c = r / 9, tap = r % 9;
    wT2[idx] = w_c2[(oc * 128 + c) * 9 + tap];
    wT3[idx] = w_c3[(oc * 128 + c) * 9 + tap];
  }
}

// k=3 pad=1 grouped conv1d + relu, 4-way channel split.
// grid.x = B*Cout, block = 512 (4 cg x 128 t)
__global__ __launch_bounds__(512) void conv1d_k3s(
    const float* __restrict__ in, const float* __restrict__ wt,
    const float* __restrict__ bias, float* __restrict__ out,
    int Cin_total, int Cin_g, int Cout, int ocpg) {
  __shared__ float part[512];
  int bo = blockIdx.x;
  int o = bo % Cout, b = bo / Cout, g = o / ocpg;
  int tid = threadIdx.x;
  int cg = __builtin_amdgcn_readfirstlane(tid >> 7);  // wave-uniform
  int t = tid & 127;
  int tc = t < 100 ? t : 99;
  int cpc = Cin_g >> 2;
  const float* ib = in + ((size_t)b * Cin_total + (size_t)g * Cin_g + (size_t)cg * cpc) * 100;
  const float* wr = wt + ((size_t)o * Cin_g + (size_t)cg * cpc) * 3;
  float acc = 0.f;
#pragma unroll 4
  for (int c = 0; c < cpc; ++c) {
    const float* row = ib + c * 100;
    float w0 = wr[c * 3 + 0], w1 = wr[c * 3 + 1], w2 = wr[c * 3 + 2];
    float a = (tc > 0) ? row[tc - 1] : 0.f;
    float m = row[tc];
    float z = (tc < 99) ? row[tc + 1] : 0.f;
    acc += w0 * a + w1 * m + w2 * z;
  }
  part[tid] = acc;
  __syncthreads();
  if (cg == 0 && t < 100) {
    float a = part[t] + part[128 + t] + part[256 + t] + part[384 + t] + bias[o];
    out[(size_t)bo * 100 + t] = fmaxf(a, 0.f);
  }
}

// dual-branch version: blocks [0,512) -> A (s-branch), [512,1024) -> B (e-branch)
__global__ __launch_bounds__(512) void conv1d_k3s_dual(
    const float* __restrict__ in,
    const float* __restrict__ wA, const float* __restrict__ bA, float* __restrict__ outA,
    const float* __restrict__ wB, const float* __restrict__ bB, float* __restrict__ outB,
    int Cin_total, int Cin_g, int Cout, int ocpg) {
  __shared__ float part[512];
  int bx = blockIdx.x;
  bool second = bx >= 512;
  int bo = second ? bx - 512 : bx;
  const float* wt = second ? wB : wA;
  const float* bias = second ? bB : bA;
  float* out = second ? outB : outA;
  int o = bo % Cout, b = bo / Cout, g = o / ocpg;
  int tid = threadIdx.x;
  int cg = __builtin_amdgcn_readfirstlane(tid >> 7);
  int t = tid & 127;
  int tc = t < 100 ? t : 99;
  int cpc = Cin_g >> 2;
  const float* ib = in + ((size_t)b * Cin_total + (size_t)g * Cin_g + (size_t)cg * cpc) * 100;
  const float* wr = wt + ((size_t)o * Cin_g + (size_t)cg * cpc) * 3;
  float acc = 0.f;
#pragma unroll 4
  for (int c = 0; c < cpc; ++c) {
    const float* row = ib + c * 100;
    float w0 = wr[c * 3 + 0], w1 = wr[c * 3 + 1], w2 = wr[c * 3 + 2];
    float a = (tc > 0) ? row[tc - 1] : 0.f;
    float m = row[tc];
    float z = (tc < 99) ? row[tc + 1] : 0.f;
    acc += w0 * a + w1 * m + w2 * z;
  }
  part[tid] = acc;
  __syncthreads();
  if (cg == 0 && t < 100) {
    float a = part[t] + part[128 + t] + part[256 + t] + part[384 + t] + bias[o];
    out[(size_t)bo * 100 + t] = fmaxf(a, 0.f);
  }
}

// dense p-conv1d, SPLIT-K raw partials. grid=(512,2), block=512 (4cg x 128t);
// kz selects channels [kz*128, kz*128+128), cg covers 32 within that.
__global__ __launch_bounds__(512) void conv1d_p_sk(
    const float* __restrict__ in, const float* __restrict__ wt,
    float* __restrict__ dst0, float* __restrict__ dst1) {
  __shared__ float part[512];
  int bo = blockIdx.x;              // b*256+o
  int kz = blockIdx.y;
  float* dst = kz ? dst1 : dst0;
  int o = bo & 255, b = bo >> 8;
  int tid = threadIdx.x;
  int cg = __builtin_amdgcn_readfirstlane(tid >> 7);
  int t = tid & 127;
  int tc = t < 100 ? t : 99;
  int cbase = kz * 128 + cg * 32;
  const float* ib = in + ((size_t)b * 256 + cbase) * 100;
  const float* wr = wt + ((size_t)o * 256 + cbase) * 3;
  float acc = 0.f;
#pragma unroll 4
  for (int c = 0; c < 32; ++c) {
    const float* row = ib + c * 100;
    float w0 = wr[c * 3 + 0], w1 = wr[c * 3 + 1], w2 = wr[c * 3 + 2];
    float a = (tc > 0) ? row[tc - 1] : 0.f;
    float m = row[tc];
    float z = (tc < 99) ? row[tc + 1] : 0.f;
    acc += w0 * a + w1 * m + w2 * z;
  }
  part[tid] = acc;
  __syncthreads();
  if (cg == 0 && t < 100) {
    float a = part[t] + part[128 + t] + part[256 + t] + part[384 + t];
    dst[(size_t)bo * 100 + t] = a;  // raw partial
  }
}

// merge p partials (float4): p = relu(p0 + p1 + bias[o]). 12800 vec4, grid=50
__global__ void merge_p_k(const float4* __restrict__ p0, const float4* __restrict__ p1,
                          const float* __restrict__ bias, float4* __restrict__ p) {
  int i = blockIdx.x * 256 + threadIdx.x;
  if (i >= 12800) return;
  int o = ((i * 4) / 100) & 255;   // 100 % 4 == 0: all 4 share o
  float bo = bias[o];
  float4 a = p0[i], b = p1[i], r;
  r.x = fmaxf(a.x + b.x + bo, 0.f);
  r.y = fmaxf(a.y + b.y + bo, 0.f);
  r.z = fmaxf(a.z + b.z + bo, 0.f);
  r.w = fmaxf(a.w + b.w + bo, 0.f);
  p[i] = r;
}

// dual 1x1->1 heads + sigmoid. grid=400: [0,200) start, [200,400) end. block=64
__global__ void head_sig_dual(const float* __restrict__ midA, const float* __restrict__ wA,
                              const float* __restrict__ bA, float* __restrict__ outA,
                              const float* __restrict__ midB, const float* __restrict__ wB,
                              const float* __restrict__ bB, float* __restrict__ outB) {
  int bx = blockIdx.x;
  bool second = bx >= 200;
  int idx = second ? bx - 200 : bx;
  const float* mid = second ? midB : midA;
  const float* w = second ? wB : wA;
  const float* bias = second ? bB : bA;
  float* out = second ? outB : outA;
  int b = idx / 100, t = idx % 100;
  int l = threadIdx.x;
  float acc = 0.f;
#pragma unroll
  for (int c0 = 0; c0 < 256; c0 += 64)
    acc += mid[((size_t)b * 256 + c0 + l) * 100 + t] * w[c0 + l];
#pragma unroll
  for (int off = 32; off; off >>= 1) acc += __shfl_down(acc, off);
  if (l == 0) out[idx] = 1.f / (1.f + expf(-(acc + bias[0])));
}

// q[b,o,n,pos] = sum_c w3d[o,c,n] p[b,c,pos]. grid = 1024 (b*512+o),
// block 512 = 4 n-groups x 128 lanes(pos); group ng owns n in [8ng, 8ng+8).
__global__ __launch_bounds__(512) void qgemm_k(
    const float* __restrict__ p, const float* __restrict__ w3d,
    float* __restrict__ q) {
  int bb = blockIdx.x;
  int b = bb >> 9, o = bb & 511;
  int tid = threadIdx.x;
  int ng = __builtin_amdgcn_readfirstlane(tid >> 7);  // wave-uniform n group
  int pos = tid & 127;
  int pc = pos < 100 ? pos : 99;
  const float* pb = p + (size_t)b * 25600;
  const float* wr = w3d + (size_t)o * 8192 + ng * 8;
  float acc[8];
#pragma unroll
  for (int j = 0; j < 8; ++j) acc[j] = 0.f;
#pragma unroll 2
  for (int c = 0; c < 256; ++c) {
    float v = pb[c * 100 + pc];
    const float* w = wr + c * 32;
#pragma unroll
    for (int j = 0; j < 8; ++j) acc[j] += v * w[j];
  }
  if (pos < 100) {
#pragma unroll
    for (int j = 0; j < 8; ++j)
      q[((size_t)(bb * 32 + ng * 8 + j)) * 100 + pos] = acc[j];
  }
}

// fmap for an o-PAIR. grid=(512,5), block 512 = 8 waves (R18 wave-tiling).
__global__ __launch_bounds__(512) void fmap_k2(
    const float* __restrict__ q, const int4* __restrict__ tab,
    const int* __restrict__ npd, const int2* __restrict__ ctab,
    const int* __restrict__ ncord, const float* __restrict__ b3d,
    float* __restrict__ out) {
  __shared__ float2 qsp[32 * PADW];  // 39424 B -> 4 blocks/CU
  int bo0 = blockIdx.x * 2;
  int bo1 = bo0 + 1;
  const float* qa = q + (size_t)bo0 * 3200;
  const float* qb = q + (size_t)bo1 * 3200;
  for (int i = threadIdx.x; i < 32 * PADW; i += 512) qsp[i] = make_float2(0.f, 0.f);
  __syncthreads();
  for (int i = threadIdx.x; i < 3200; i += 512) {
    int n = i / 100;
    qsp[n * PADW + PADL + (i - n * 100)] = make_float2(qa[i], qb[i]);
  }
  __syncthreads();
  int w = __builtin_amdgcn_readfirstlane(threadIdx.x >> 6);  // wave id 0..7
  int lane = threadIdx.x & 63;
  int dbase = __builtin_amdgcn_readfirstlane(blockIdx.y * 20);
  int v1 = 36 - dbase;
  v1 = v1 < 0 ? 0 : (v1 > 20 ? 20 : v1);   // half-1 tiles with any valid lane
  int ntiles = 20 + v1;
  float biasA = b3d[bo0 & 511];
  float biasB = b3d[bo1 & 511];
  for (int tt = w; tt < ntiles; tt += 8) {   // wave-uniform loop
    int half = tt >= 20;
    int d = __builtin_amdgcn_readfirstlane(dbase + (half ? tt - 20 : tt));
    int s = (half << 6) + lane;
    int sc = s < 100 ? s : 99;
    const int4* td = tab + d * 96;
    int np = npd[d];
    float a0 = 0.f, a1 = 0.f, b0 = 0.f, b1 = 0.f;
    for (int j = 0; j < np; ++j) {
      int4 e = td[j];     // s_load (uniform): ofs+weights+cap in SGPRs
      int i0 = min(e.x + sc, e.w);   // clamp into per-row zero cells
      float2 v0 = qsp[i0];
      float2 v1f = qsp[i0 + 1];
      float w0 = __int_as_float(e.y);
      float w1 = __int_as_float(e.z);
      a0 += w0 * v0.x;
      b0 += w0 * v0.y;
      a1 += w1 * v1f.x;
      b1 += w1 * v1f.y;
    }
    if (!half) {  // corrections only target lanes s <= 50
      const int2* cd = ctab + d * 64;
      int nc = ncord[d];
      for (int j = 0; j < nc; ++j) {
        int2 c = cd[j];   // s_load
        int addr = c.x & 0xFFFF;
        int st = c.x >> 16;
        float wgt = (s == st) ? __int_as_float(c.y) : 0.f;
        float2 v = qsp[addr];
        a0 += wgt * v.x;
        b0 += wgt * v.y;
      }
    }
    if (s < 100) {
      bool valid = (s + d < 100);
      float preA = biasA + (valid ? (a0 + a1) : 0.f);
      float preB = biasB + (valid ? (b0 + b1) : 0.f);
      out[((size_t)bo0 * 100 + d) * 100 + s] = fmaxf(preA, 0.f);
      out[((size_t)bo1 * 100 + d) * 100 + s] = fmaxf(preB, 0.f);
    }
  }
  // dead region: half-1 tiles for d in [dbase+v1, dbase+20), s in [64,100)
  int ndead = (20 - v1) * 36;
  float cA = fmaxf(biasA, 0.f);
  float cB = fmaxf(biasB, 0.f);
  for (int idx = threadIdx.x; idx < ndead; idx += 512) {
    int dd = idx / 36;
    int ss = 64 + idx - dd * 36;
    int d = dbase + v1 + dd;
    out[((size_t)bo0 * 100 + d) * 100 + ss] = cA;
    out[((size_t)bo1 * 100 + d) * 100 + ss] = cB;
  }
}

// 1x1 conv 512->128, SPLIT-K raw partials. grid=(200,8,2), block=128, 16 oc;
// kz selects c-range [kz*256,(kz+1)*256); dst0 for kz=0, dst1 for kz=1.
__global__ void conv1x1_sk(const float* __restrict__ in, const float* __restrict__ wT,
                           float* __restrict__ dst0, float* __restrict__ dst1) {
  int bd = blockIdx.x;
  int y = bd % 100;
  int b = bd / 100;
  int oc0 = blockIdx.y * 16;
  int kz = blockIdx.z;
  float* dst = kz ? dst1 : dst0;
  int t = threadIdx.x;
  int tc = t < 100 ? t : 99;
  float acc[16];
#pragma unroll
  for (int j = 0; j < 16; ++j) acc[j] = 0.f;
  const float* inb = in + (size_t)b * 5120000 + (size_t)(kz * 256) * 10000 +
                     (size_t)y * 100 + tc;
  const float* wb = wT + (size_t)(kz * 256) * 128;
  for (int c = 0; c < 256; ++c) {
    float v = inb[(size_t)c * 10000];
    const float* w = wb + c * 128 + oc0;
#pragma unroll
    for (int j = 0; j < 16; ++j) acc[j] += v * w[j];
  }
  if (t < 100) {
#pragma unroll
    for (int j = 0; j < 16; ++j)
      dst[((size_t)(b * 128 + oc0 + j) * 100 + y) * 100 + t] = acc[j];
  }
}

// 3x3 conv 128->128 pad 1, SPLIT-K(3) raw partials (R19 proven).
// grid=(200,8,3), block=128, 16 oc; kz c-ranges {0..42, 43..85, 86..127}.
__global__ void conv3x3_sk3(const float* __restrict__ in, const float* __restrict__ wT,
                            float* __restrict__ dst0, float* __restrict__ dst1,
                            float* __restrict__ dst2) {
  int bd = blockIdx.x;
  int y = bd % 100;
  int b = bd / 100;
  int oc0 = blockIdx.y * 16;
  int kz = blockIdx.z;
  int c0 = kz * 43;
  int cend = (kz == 2) ? 128 : c0 + 43;
  float* dst = (kz == 0) ? dst0 : ((kz == 1) ? dst1 : dst2);
  int t = threadIdx.x;
  int tc = t < 100 ? t : 99;
  float acc[16];
#pragma unroll
  for (int j = 0; j < 16; ++j) acc[j] = 0.f;
  for (int c = c0; c < cend; ++c) {
    const float* ib = in + ((size_t)(b * 128 + c)) * 10000;
#pragma unroll
    for (int ky = 0; ky < 3; ++ky) {
      int yy = y + ky - 1;
      if ((unsigned)yy > 99u) continue;
      const float* row = ib + (size_t)yy * 100;
      float vm = (tc > 0) ? row[tc - 1] : 0.f;
      float v0 = row[tc];
      float vp = (tc < 99) ? row[tc + 1] : 0.f;
      const float* w = wT + ((size_t)(c * 3 + ky) * 3) * 128 + oc0;
#pragma unroll
      for (int j = 0; j < 16; ++j) acc[j] += vm * w[j];
#pragma unroll
      for (int j = 0; j < 16; ++j) acc[j] += v0 * w[128 + j];
#pragma unroll
      for (int j = 0; j < 16; ++j) acc[j] += vp * w[256 + j];
    }
  }
  if (t < 100) {
#pragma unroll
    for (int j = 0; j < 16; ++j)
      dst[((size_t)(b * 128 + oc0 + j) * 100 + y) * 100 + t] = acc[j];
  }
}

// merge 2 split-K partials (float4): io = relu(io + pA + bias[oc]).
// 640000 vec4, grid=2500. 10000 % 4 == 0 -> all 4 elems share oc.
__global__ void merge_relu_k(const float4* __restrict__ pA, float4* __restrict__ io,
                             const float* __restrict__ bias) {
  int i = blockIdx.x * 256 + threadIdx.x;
  if (i >= 640000) return;
  int oc = ((i * 4) / 10000) & 127;
  float bo = bias[oc];
  float4 a = pA[i], b = io[i], r;
  r.x = fmaxf(a.x + b.x + bo, 0.f);
  r.y = fmaxf(a.y + b.y + bo, 0.f);
  r.z = fmaxf(a.z + b.z + bo, 0.f);
  r.w = fmaxf(a.w + b.w + bo, 0.f);
  io[i] = r;
}

// merge 3 split-K partials (float4): io = relu(io + pA + pB + bias[oc]).
__global__ void merge_relu3_k(const float4* __restrict__ pA, const float4* __restrict__ pB,
                              float4* __restrict__ io, const float* __restrict__ bias) {
  int i = blockIdx.x * 256 + threadIdx.x;
  if (i >= 640000) return;
  int oc = ((i * 4) / 10000) & 127;
  float bo = bias[oc];
  float4 a = pA[i], b = pB[i], c = io[i], r;
  r.x = fmaxf(a.x + b.x + c.x + bo, 0.f);
  r.y = fmaxf(a.y + b.y + c.y + bo, 0.f);
  r.z = fmaxf(a.z + b.z + c.z + bo, 0.f);
  r.w = fmaxf(a.w + b.w + c.w + bo, 0.f);
  io[i] = r;
}

// final 1x1 conv 128->2 + sigmoid. grid=625, block=256 (64 sp x 4 c-groups)
__global__ void conv1x1_final(const float* __restrict__ in, const float* __restrict__ w,
                              const float* __restrict__ bias, float* __restrict__ out) {
  __shared__ float part[256];
  int tid = threadIdx.x;
  int spl = tid & 63, cg = tid >> 6;
  int idx = blockIdx.x * 64 + spl;
  bool ok = idx < 40000;
  int ic = ok ? idx : 0;
  int sp = ic % 10000;
  int i = (ic / 10000) & 1;
  int b = ic / 20000;
  const float* ib = in + (size_t)b * 1280000 + (size_t)cg * 320000 + sp;
  const float* wp = w + i * 128 + cg * 32;
  float acc = 0.f;
#pragma unroll 8
  for (int c = 0; c < 32; ++c)
    acc += ib[(size_t)c * 10000] * wp[c];
  part[tid] = acc;
  __syncthreads();
  if (cg == 0 && ok) {
    float a = part[spl] + part[64 + spl] + part[128 + spl] + part[192 + spl] + bias[i];
    out[idx] = 1.f / (1.f + expf(-a));
  }
}

extern "C" void kernel_launch(void* const* d_in, const int* in_sizes, int n_in,
                              void* d_out, int out_size, void* d_ws, size_t ws_size,
                              hipStream_t stream) {
  const float* x    = (const float*)d_in[0];
  const float* w_b1 = (const float*)d_in[1];
  const float* b_b1 = (const float*)d_in[2];
  const float* w_b2 = (const float*)d_in[3];
  const float* b_b2 = (const float*)d_in[4];
  const float* w_s1 = (const float*)d_in[5];
  const float* b_s1 = (const float*)d_in[6];
  const float* w_s2 = (const float*)d_in[7];
  const float* b_s2 = (const float*)d_in[8];
  const float* w_e1 = (const float*)d_in[9];
  const float* b_e1 = (const float*)d_in[10];
  const float* w_e2 = (const float*)d_in[11];
  const float* b_e2 = (const float*)d_in[12];
  const float* w_p  = (const float*)d_in[13];
  const float* b_p  = (const float*)d_in[14];
  const float* w_3d = (const float*)d_in[15];
  const float* b_3d = (const float*)d_in[16];
  const float* w_c1 = (const float*)d_in[17];
  const float* b_c1 = (const float*)d_in[18];
  const float* w_c2 = (const float*)d_in[19];
  const float* b_c2 = (const float*)d_in[20];
  const float* w_c3 = (const float*)d_in[21];
  const float* b_c3 = (const float*)d_in[22];
  const float* w_c4 = (const float*)d_in[23];
  const float* b_c4 = (const float*)d_in[24];
  // d_in[25] = sample_mask (unused: replaced by analytic table)

  float* out = (float*)d_out;
  float* ws  = (float*)d_ws;

  // workspace layout (float offsets); peak 10,959,104 floats = 43.8 MB
  float* h1  = ws;                        // 51200
  float* h2  = ws + 51200;                // 51200
  float* mid = ws + 102400;               // 51200 (s-branch)
  float* p   = ws + 153600;               // 51200
  int4*  tab   = (int4*)(ws + 204800);    // 9600 int4 = 38400
  int*   npd   = (int*)(ws + 243200);     // 128
  int2*  ctab  = (int2*)(ws + 243328);    // 6400 int2 = 12800
  int*   ncord = (int*)(ws + 256128);     // 128
  float* wT1 = ws + 256256;               // 65536
  float* wT2 = ws + 321792;               // 147456
  float* wT3 = ws + 469248;               // 147456
  float* q   = ws + 616704;               // 3,276,800 (dead after fmap_k2)
  float* c1b = ws + 616704;               // 2,560,000 (reuses q)
  float* c2b = ws + 3176704;              // 2,560,000
  float* mid_e = ws + 3176704;            // 51200 (dead before c2b written)
  float* pA  = ws + 5736704;              // 2,560,000 (split-K partial)
  float* pP0 = ws + 8296704;              // 51200 (p-conv partial kz=0)
  float* pP1 = ws + 8347904;              // 51200 (p-conv partial kz=1)
  float* pB  = ws + 8399104;              // 2,560,000 (split-K partial #2)

  float* out_conf  = out;                 // 40,000
  float* out_start = out + 40000;         // 200
  float* out_end   = out + 40200;         // 200
  float* out_fmap  = out + 40400;         // 10,240,000

  hipLaunchKernelGGL(build_table_k, dim3(1), dim3(128), 0, stream,
                     tab, npd, ctab, ncord);
  hipLaunchKernelGGL(prep_w_k, dim3(576), dim3(256), 0, stream,
                     w_c1, w_c2, w_c3, wT1, wT2, wT3);

  hipLaunchKernelGGL(conv1d_k3s, dim3(512), dim3(512), 0, stream,
                     x, w_b1, b_b1, h1, 400, 100, 256, 64);
  hipLaunchKernelGGL(conv1d_k3s, dim3(512), dim3(512), 0, stream,
                     h1, w_b2, b_b2, h2, 256, 64, 256, 64);

  hipLaunchKernelGGL(conv1d_k3s_dual, dim3(1024), dim3(512), 0, stream,
                     h2, w_s1, b_s1, mid, w_e1, b_e1, mid_e, 256, 64, 256, 64);
  hipLaunchKernelGGL(head_sig_dual, dim3(400), dim3(64), 0, stream,
                     mid, w_s2, b_s2, out_start, mid_e, w_e2, b_e2, out_end);

  // dense p-conv: split-K partials + merge
  hipLaunchKernelGGL(conv1d_p_sk, dim3(512, 2), dim3(512), 0, stream,
                     h2, w_p, pP0, pP1);
  hipLaunchKernelGGL(merge_p_k, dim3(50), dim3(256), 0, stream,
                     (const float4*)pP0, (const float4*)pP1, b_p, (float4*)p);

  hipLaunchKernelGGL(qgemm_k, dim3(1024), dim3(512), 0, stream, p, w_3d, q);

  hipLaunchKernelGGL(fmap_k2, dim3(512, 5), dim3(512), 0, stream,
                     q, tab, npd, ctab, ncord, b_3d, out_fmap);

  // conv1x1: split-K partials (kz=0 -> pA, kz=1 -> c1b), merge into c1b
  hipLaunchKernelGGL(conv1x1_sk, dim3(200, 8, 2), dim3(128), 0, stream,
                     out_fmap, wT1, pA, c1b);
  hipLaunchKernelGGL(merge_relu_k, dim3(2500), dim3(256), 0, stream,
                     (const float4*)pA, (float4*)c1b, b_c1);

  // conv3x3 layer 1: kz=3 partials (pA, pB, c2b), 3-way merge into c2b
  hipLaunchKernelGGL(conv3x3_sk3, dim3(200, 8, 3), dim3(128), 0, stream,
                     c1b, wT2, pA, pB, c2b);
  hipLaunchKernelGGL(merge_relu3_k, dim3(2500), dim3(256), 0, stream,
                     (const float4*)pA, (const float4*)pB, (float4*)c2b, b_c2);

  // conv3x3 layer 2: input c2b; kz=3 partials (pA, pB, c1b), merge c1b
  hipLaunchKernelGGL(conv3x3_sk3, dim3(200, 8, 3), dim3(128), 0, stream,
                     c2b, wT3, pA, pB, c1b);
  hipLaunchKernelGGL(merge_relu3_k, dim3(2500), dim3(256), 0, stream,
                     (const float4*)pA, (const float4*)pB, (float4*)c1b, b_c3);

  hipLaunchKernelGGL(conv1x1_final, dim3(625), dim3(256), 0, stream,
                     c1b, w_c4, b_c4, out_conf);
}